// Round 8
// baseline (1011.812 us; speedup 1.0000x reference)
//
#include <hip/hip_runtime.h>
#include <hip/hip_bf16.h>
#include <hip/hip_fp16.h>

typedef _Float16 half8 __attribute__((ext_vector_type(8)));
typedef _Float16 half4 __attribute__((ext_vector_type(4)));
typedef __fp16 fp16x2 __attribute__((ext_vector_type(2)));
typedef float floatx4 __attribute__((ext_vector_type(4)));

#define HID 128
#define TILE_M 32

__device__ __forceinline__ float fast_silu(float v) {
    float e = __expf(-v);
    return v * __builtin_amdgcn_rcpf(1.f + e);
}

__device__ __forceinline__ unsigned int pk2(float a, float b) {
    fp16x2 h = __builtin_amdgcn_cvt_pkrtz(a, b);
    return __builtin_bit_cast(unsigned int, h);
}

// LDS-only barrier: drains LDS ops but leaves global (vmcnt) traffic in
// flight. Use ONLY where the barrier guards LDS-LDS hazards exclusively.
__device__ __forceinline__ void barrier_lds_only() {
    asm volatile("s_waitcnt lgkmcnt(0)\n\ts_barrier" ::: "memory");
}

// ---------------------------------------------------------------------------
// Kernel 1: node_emb = [x|pos|0-pad] @ [Wa;Wp;0] + (ba+bp). Block handles a
// 64-node tile via MFMA; output assembled in padded LDS, stored coalesced.
// ---------------------------------------------------------------------------
#define LDO 136
__global__ __launch_bounds__(256) void node_emb_kernel(
    const float* __restrict__ x, const float* __restrict__ pos,
    const float* __restrict__ Wa, const float* __restrict__ ba,
    const float* __restrict__ Wp, const float* __restrict__ bp,
    _Float16* __restrict__ nodeEmb, int N)
{
    __shared__ __align__(16) _Float16 sOut[64 * LDO];   // 17 KB
    const int t    = threadIdx.x;
    const int wave = t >> 6;
    const int lane = t & 63;
    const int quad = lane >> 4;
    const int l16  = lane & 15;

    half8 wf[2];
    floatx4 bias[2];
    #pragma unroll
    for (int ct = 0; ct < 2; ++ct) {
        int col = wave * 32 + ct * 16 + l16;
        #pragma unroll
        for (int j = 0; j < 8; ++j) {
            int k = quad * 8 + j;
            float w = 0.f;
            if (k < 16) w = Wa[k * HID + col];
            else if (k < 19) w = Wp[(k - 16) * HID + col];
            wf[ct][j] = (_Float16)w;
        }
        #pragma unroll
        for (int i = 0; i < 4; ++i) {
            int c2 = wave * 32 + ct * 16 + quad * 4 + i;
            bias[ct][i] = ba[c2] + bp[c2];
        }
    }

    int nTiles = (N + 63) >> 6;
    for (int tile = blockIdx.x; tile < nTiles; tile += gridDim.x) {
        int base = tile * 64;
        half8 af[4];
        #pragma unroll
        for (int rt = 0; rt < 4; ++rt) {
            int node = base + rt * 16 + l16;
            int nd = node < N ? node : N - 1;
            half8 a = (half8){0, 0, 0, 0, 0, 0, 0, 0};
            if (quad < 2) {
                const float* xp = x + (size_t)nd * 16 + quad * 8;
                float4 v0 = *(const float4*)xp;
                float4 v1 = *(const float4*)(xp + 4);
                a[0] = (_Float16)v0.x; a[1] = (_Float16)v0.y;
                a[2] = (_Float16)v0.z; a[3] = (_Float16)v0.w;
                a[4] = (_Float16)v1.x; a[5] = (_Float16)v1.y;
                a[6] = (_Float16)v1.z; a[7] = (_Float16)v1.w;
            } else if (quad == 2) {
                const float* pp = pos + (size_t)nd * 3;
                a[0] = (_Float16)pp[0]; a[1] = (_Float16)pp[1]; a[2] = (_Float16)pp[2];
            }
            af[rt] = a;
        }
        #pragma unroll
        for (int ct = 0; ct < 2; ++ct)
            #pragma unroll
            for (int rt = 0; rt < 4; ++rt) {
                floatx4 d = bias[ct];
                d = __builtin_amdgcn_mfma_f32_16x16x32_f16(wf[ct], af[rt], d, 0, 0, 0);
                half4 hv;
                hv[0] = (_Float16)d[0]; hv[1] = (_Float16)d[1];
                hv[2] = (_Float16)d[2]; hv[3] = (_Float16)d[3];
                *(half4*)&sOut[(rt * 16 + l16) * LDO + wave * 32 + ct * 16 + quad * 4] = hv;
            }
        __syncthreads();
        #pragma unroll
        for (int p = 0; p < 4; ++p) {
            int idx = p * 256 + t;
            int r = idx >> 4, c = idx & 15;
            int node = base + r;
            if (node < N)
                *(half8*)(nodeEmb + (size_t)node * HID + c * 8) =
                    *(const half8*)&sOut[r * LDO + c * 8];
        }
        __syncthreads();
    }
}

// ---------------------------------------------------------------------------
// Kernel 2: per-edge MLP. TILE_M=32, 512 threads = 8 waves x 16 output cols.
// Round-6's proven 2-barrier pipeline (sH1/sH2 SEPARATE — no extra barriers),
// tile halved so MAX occupancy fits: LDS 16K(sA)+8K+8K+sW3+sDist ~= 34 KB ->
// 4 blocks/CU (136 KB <= 134 KB-proven pool... 4x34.2=136.9 <= 160; round-6
// proved >=134 usable) x 8 waves = 32 waves/CU = 8 waves/SIMD (the max).
// VGPR: accumulators halve vs round-6 (acc[2],acc2[2]) so demand < 64;
// launch_bounds(512,8) caps allocator at exactly 64 = round-6's achieved
// count. Per-edge work unchanged; barrier rate doubles but 4 independent
// block domains/CU cross-hide the stalls. VALU (the 50%-busy dominant pipe
// at 4 waves/SIMD) should approach saturation at 8.
// Verify: VGPR=64 & WRITE ~41MB (no spill), LDS ~34.5KB, Occupancy 65-80%.
// ---------------------------------------------------------------------------
__global__ __launch_bounds__(512, 8) void edge_mlp_kernel(
    const _Float16* __restrict__ nodeEmb,
    const float* __restrict__ pos,
    const int* __restrict__ eidx,          // [2][E]
    const float* __restrict__ W1, const float* __restrict__ b1,   // [257][128]
    const float* __restrict__ W2, const float* __restrict__ b2,   // [128][128]
    const float* __restrict__ W3, const float* __restrict__ b3,   // [128][4]
    float* __restrict__ out, int E, int nTiles)
{
    __shared__ __align__(16) _Float16 sA[2 * TILE_M * HID];   // 16 KB, XOR swizzle
    __shared__ __align__(16) _Float16 sH1[TILE_M * HID];      // 8 KB, XOR swizzle
    __shared__ __align__(16) _Float16 sH2[TILE_M * HID];      // 8 KB, XOR swizzle
    __shared__ float sDist[TILE_M];
    __shared__ __align__(16) _Float16 sW3[512];               // 1 KB  W3 frags

    const int t    = threadIdx.x;
    const int wave = t >> 6;               // 0..7
    const int lane = t & 63;
    const int quad = lane >> 4;
    const int l16  = lane & 15;
    const int colbase = wave * 16;         // each wave owns 16 output columns

    // ---- stage W3 fragment table into LDS (visible after first B1) ----
    if (t < 64) {
        int kc = t >> 4, q = (t >> 2) & 3, c = t & 3;
        #pragma unroll
        for (int j = 0; j < 8; ++j)
            sW3[(kc * 16 + q * 4 + c) * 8 + j] =
                (_Float16)W3[(kc * 32 + q * 8 + j) * 4 + c];
    }

    // ---- weight fragments (frag[j] = W[k0+quad*8+j][col]), 1 col-tile/wave ----
    half8 w1f[8];                          // 32 VGPR
    half8 w2f[4];                          // 16 VGPR
    float w1c[4], b1f[4], b2f[4];
    {
        int col = colbase + l16;
        #pragma unroll
        for (int kc = 0; kc < 8; ++kc)
            #pragma unroll
            for (int j = 0; j < 8; ++j)
                w1f[kc][j] = (_Float16)W1[(kc * 32 + quad * 8 + j) * HID + col];
        #pragma unroll
        for (int kc = 0; kc < 4; ++kc)
            #pragma unroll
            for (int j = 0; j < 8; ++j)
                w2f[kc][j] = (_Float16)W2[(kc * 32 + quad * 8 + j) * HID + col];
        #pragma unroll
        for (int i = 0; i < 4; ++i) {
            int c2 = colbase + quad * 4 + i;
            w1c[i] = W1[256 * HID + c2];
            b1f[i] = b1[c2];
            b2f[i] = b2[c2];
        }
    }
    const float b3v0 = b3[0], b3v1 = b3[1], b3v2 = b3[2], b3v3 = b3[3];

    int nid[2];
    float dpre = 0.f;

    auto load_nid = [&](int tl) {
        int eb = tl * TILE_M;
        #pragma unroll
        for (int i = 0; i < 2; ++i) {
            int cid = i * 512 + t;           // 0..1023 chunks of 16B
            int row = cid >> 4;              // 0..63: 0-31 src, 32-63 dst
            int r   = row & 31;
            int e   = eb + r; if (e >= E) e = E - 1;
            nid[i] = (row >> 5) ? eidx[(size_t)E + e] : eidx[e];
        }
    };
    auto load_dist = [&](int tl) -> float {
        if (t >= TILE_M) return 0.f;
        int e = tl * TILE_M + t; if (e >= E) e = E - 1;
        int s = eidx[e], d = eidx[(size_t)E + e];
        float dx = pos[3 * (size_t)s]     - pos[3 * (size_t)d];
        float dy = pos[3 * (size_t)s + 1] - pos[3 * (size_t)d + 1];
        float dz = pos[3 * (size_t)s + 2] - pos[3 * (size_t)d + 2];
        return sqrtf(dx * dx + dy * dy + dz * dz);
    };
    auto dma_issue = [&]() {
        #pragma unroll
        for (int i = 0; i < 2; ++i) {
            int cid = i * 512 + t;
            int row = cid >> 4;
            int cg  = (cid & 15) ^ (row & 15);      // XOR swizzle
            const _Float16* gp = nodeEmb + (size_t)nid[i] * HID + cg * 8;
            __builtin_amdgcn_global_load_lds(
                (__attribute__((address_space(1))) void*)gp,
                (__attribute__((address_space(3))) void*)&sA[(i * 512 + (t & 448)) * 8],
                16, 0, 0);
        }
    };

    bool havePrev = false;
    int prevEbase = 0;
    int tile = blockIdx.x;
    if (tile < nTiles) {
        load_nid(tile);
        dpre = load_dist(tile);
        dma_issue();                         // drains at first B1
    }

    for (; tile < nTiles; tile += gridDim.x) {
        const int ebase = tile * TILE_M;
        if (t < TILE_M) sDist[t] = dpre;
        __syncthreads();                     // B1: DMA(T) drained, sH2(T-1) ready

        // ---- layer 3 of previous tile: waves 0-1 cover the 32 edges ----
        if (havePrev && wave < 2) {
            floatx4 acc3 = (floatx4){0.f, 0.f, 0.f, 0.f};
            #pragma unroll
            for (int kc = 0; kc < 4; ++kc) {
                int slot = ((kc * 4 + quad) ^ l16) * 8;
                half8 h  = *(const half8*)&sH2[(wave * 16 + l16) * HID + slot];
                half8 w3 = *(const half8*)&sW3[(kc * 16 + quad * 4 + (l16 & 3)) * 8];
                acc3 = __builtin_amdgcn_mfma_f32_16x16x32_f16(w3, h, acc3, 0, 0, 0);
            }
            if (quad == 0) {
                int e = prevEbase + wave * 16 + l16;
                if (e < E) {
                    float4 o = {acc3[0] + b3v0, acc3[1] + b3v1,
                                acc3[2] + b3v2, acc3[3] + b3v3};
                    *(float4*)&out[(size_t)e * 4] = o;
                }
            }
        }

        // ---- prefetch next tile metadata (DMA issued post-B2) ----
        int nxt = tile + gridDim.x;
        if (nxt < nTiles) {
            load_nid(nxt);
            dpre = load_dist(nxt);
        }

        // ---- layer 1: bias in acc init, XOR-swizzled sA reads ----
        floatx4 acc[2];
        #pragma unroll
        for (int rt = 0; rt < 2; ++rt) {
            acc[rt][0] = b1f[0]; acc[rt][1] = b1f[1];
            acc[rt][2] = b1f[2]; acc[rt][3] = b1f[3];
        }
        #pragma unroll
        for (int kc = 0; kc < 8; ++kc) {
            int hf   = kc >> 2;
            int cg   = (kc & 3) * 4 + quad;
            int slot = (cg ^ l16) * 8;
            const _Float16* base = &sA[(hf * TILE_M + l16) * HID + slot];
            half8 a0 = *(const half8*)(base + 0 * 16 * HID);
            half8 a1 = *(const half8*)(base + 1 * 16 * HID);
            acc[0] = __builtin_amdgcn_mfma_f32_16x16x32_f16(w1f[kc], a0, acc[0], 0, 0, 0);
            acc[1] = __builtin_amdgcn_mfma_f32_16x16x32_f16(w1f[kc], a1, acc[1], 0, 0, 0);
        }
        // epilogue 1 -> sH1 (XOR-swizzled uint2 writes)
        #pragma unroll
        for (int rt = 0; rt < 2; ++rt) {
            int m = rt * 16 + l16;
            float d = sDist[m];
            float v0 = fast_silu(fmaf(d, w1c[0], acc[rt][0]));
            float v1 = fast_silu(fmaf(d, w1c[1], acc[rt][1]));
            float v2 = fast_silu(fmaf(d, w1c[2], acc[rt][2]));
            float v3 = fast_silu(fmaf(d, w1c[3], acc[rt][3]));
            uint2 w;
            w.x = pk2(v0, v1);
            w.y = pk2(v2, v3);
            int cgb  = wave * 2 + (quad >> 1);
            int slot = cgb ^ l16;
            *(uint2*)&sH1[m * HID + slot * 8 + (quad & 1) * 4] = w;
        }
        barrier_lds_only();                  // B2: LDS-only; prefetch loads live

        // ---- async DMA for next tile (sA free; overlaps L2+L3+next B1) ----
        if (nxt < nTiles) dma_issue();

        // ---- layer 2 ----
        floatx4 acc2[2];
        #pragma unroll
        for (int rt = 0; rt < 2; ++rt) {
            acc2[rt][0] = b2f[0]; acc2[rt][1] = b2f[1];
            acc2[rt][2] = b2f[2]; acc2[rt][3] = b2f[3];
        }
        #pragma unroll
        for (int kc = 0; kc < 4; ++kc) {
            int slot = ((kc * 4 + quad) ^ l16) * 8;
            half8 a0 = *(const half8*)&sH1[(0 * 16 + l16) * HID + slot];
            half8 a1 = *(const half8*)&sH1[(1 * 16 + l16) * HID + slot];
            acc2[0] = __builtin_amdgcn_mfma_f32_16x16x32_f16(w2f[kc], a0, acc2[0], 0, 0, 0);
            acc2[1] = __builtin_amdgcn_mfma_f32_16x16x32_f16(w2f[kc], a1, acc2[1], 0, 0, 0);
        }
        // epilogue 2 -> sH2 (all waves' L3(T-1) reads finished before B2)
        #pragma unroll
        for (int rt = 0; rt < 2; ++rt) {
            int m = rt * 16 + l16;
            float v0 = fast_silu(acc2[rt][0]);
            float v1 = fast_silu(acc2[rt][1]);
            float v2 = fast_silu(acc2[rt][2]);
            float v3 = fast_silu(acc2[rt][3]);
            uint2 w;
            w.x = pk2(v0, v1);
            w.y = pk2(v2, v3);
            int cgb  = wave * 2 + (quad >> 1);
            int slot = cgb ^ l16;
            *(uint2*)&sH2[m * HID + slot * 8 + (quad & 1) * 4] = w;
        }
        havePrev = true;
        prevEbase = ebase;
    }

    // ---- flush: layer 3 of the final tile ----
    if (havePrev) {
        __syncthreads();
        if (wave < 2) {
            floatx4 acc3 = (floatx4){0.f, 0.f, 0.f, 0.f};
            #pragma unroll
            for (int kc = 0; kc < 4; ++kc) {
                int slot = ((kc * 4 + quad) ^ l16) * 8;
                half8 h  = *(const half8*)&sH2[(wave * 16 + l16) * HID + slot];
                half8 w3 = *(const half8*)&sW3[(kc * 16 + quad * 4 + (l16 & 3)) * 8];
                acc3 = __builtin_amdgcn_mfma_f32_16x16x32_f16(w3, h, acc3, 0, 0, 0);
            }
            if (quad == 0) {
                int e = prevEbase + wave * 16 + l16;
                if (e < E) {
                    float4 o = {acc3[0] + b3v0, acc3[1] + b3v1,
                                acc3[2] + b3v2, acc3[3] + b3v3};
                    *(float4*)&out[(size_t)e * 4] = o;
                }
            }
        }
    }
}

extern "C" void kernel_launch(void* const* d_in, const int* in_sizes, int n_in,
                              void* d_out, int out_size, void* d_ws, size_t ws_size,
                              hipStream_t stream) {
    const float* x   = (const float*)d_in[0];
    const float* pos = (const float*)d_in[1];
    const int*  eidx = (const int*)d_in[2];
    const float* Wa = (const float*)d_in[3];
    const float* ba = (const float*)d_in[4];
    const float* Wp = (const float*)d_in[5];
    const float* bp = (const float*)d_in[6];
    const float* W1 = (const float*)d_in[7];
    const float* b1 = (const float*)d_in[8];
    const float* W2 = (const float*)d_in[9];
    const float* b2 = (const float*)d_in[10];
    const float* W3 = (const float*)d_in[11];
    const float* b3 = (const float*)d_in[12];
    float* out = (float*)d_out;

    int N = in_sizes[0] / 16;   // ATOM_DIM
    int E = in_sizes[2] / 2;

    _Float16* nodeEmb = (_Float16*)d_ws;   // N*128 fp16 = 25.6 MB

    int nodeTiles = (N + 63) / 64;
    node_emb_kernel<<<nodeTiles, 256, 0, stream>>>(x, pos, Wa, ba, Wp, bp, nodeEmb, N);

    int nTiles = (E + TILE_M - 1) / TILE_M;
    // 4 blocks/CU x 256 CUs, 512 threads each
    edge_mlp_kernel<<<1024, 512, 0, stream>>>(nodeEmb, pos, eidx,
                                              W1, b1, W2, b2, W3, b3,
                                              out, E, nTiles);
}

// Round 11
// 344.432 us; speedup vs baseline: 2.9376x; 2.9376x over previous
//
#include <hip/hip_runtime.h>
#include <hip/hip_bf16.h>
#include <hip/hip_fp16.h>

typedef _Float16 half8 __attribute__((ext_vector_type(8)));
typedef _Float16 half4 __attribute__((ext_vector_type(4)));
typedef __fp16 fp16x2 __attribute__((ext_vector_type(2)));
typedef float floatx4 __attribute__((ext_vector_type(4)));

#define HID 128
#define TILE_M 32

__device__ __forceinline__ float fast_silu(float v) {
    float e = __expf(-v);
    return v * __builtin_amdgcn_rcpf(1.f + e);
}

__device__ __forceinline__ unsigned int pk2(float a, float b) {
    fp16x2 h = __builtin_amdgcn_cvt_pkrtz(a, b);
    return __builtin_bit_cast(unsigned int, h);
}

// ---------------------------------------------------------------------------
// Kernel 1: node_emb = [x|pos|0-pad] @ [Wa;Wp;0] + (ba+bp). Block handles a
// 64-node tile via MFMA; output assembled in padded LDS, stored coalesced.
// ---------------------------------------------------------------------------
#define LDO 136
__global__ __launch_bounds__(256) void node_emb_kernel(
    const float* __restrict__ x, const float* __restrict__ pos,
    const float* __restrict__ Wa, const float* __restrict__ ba,
    const float* __restrict__ Wp, const float* __restrict__ bp,
    _Float16* __restrict__ nodeEmb, int N)
{
    __shared__ __align__(16) _Float16 sOut[64 * LDO];   // 17 KB
    const int t    = threadIdx.x;
    const int wave = t >> 6;
    const int lane = t & 63;
    const int quad = lane >> 4;
    const int l16  = lane & 15;

    half8 wf[2];
    floatx4 bias[2];
    #pragma unroll
    for (int ct = 0; ct < 2; ++ct) {
        int col = wave * 32 + ct * 16 + l16;
        #pragma unroll
        for (int j = 0; j < 8; ++j) {
            int k = quad * 8 + j;
            float w = 0.f;
            if (k < 16) w = Wa[k * HID + col];
            else if (k < 19) w = Wp[(k - 16) * HID + col];
            wf[ct][j] = (_Float16)w;
        }
        #pragma unroll
        for (int i = 0; i < 4; ++i) {
            int c2 = wave * 32 + ct * 16 + quad * 4 + i;
            bias[ct][i] = ba[c2] + bp[c2];
        }
    }

    int nTiles = (N + 63) >> 6;
    for (int tile = blockIdx.x; tile < nTiles; tile += gridDim.x) {
        int base = tile * 64;
        half8 af[4];
        #pragma unroll
        for (int rt = 0; rt < 4; ++rt) {
            int node = base + rt * 16 + l16;
            int nd = node < N ? node : N - 1;
            half8 a = (half8){0, 0, 0, 0, 0, 0, 0, 0};
            if (quad < 2) {
                const float* xp = x + (size_t)nd * 16 + quad * 8;
                float4 v0 = *(const float4*)xp;
                float4 v1 = *(const float4*)(xp + 4);
                a[0] = (_Float16)v0.x; a[1] = (_Float16)v0.y;
                a[2] = (_Float16)v0.z; a[3] = (_Float16)v0.w;
                a[4] = (_Float16)v1.x; a[5] = (_Float16)v1.y;
                a[6] = (_Float16)v1.z; a[7] = (_Float16)v1.w;
            } else if (quad == 2) {
                const float* pp = pos + (size_t)nd * 3;
                a[0] = (_Float16)pp[0]; a[1] = (_Float16)pp[1]; a[2] = (_Float16)pp[2];
            }
            af[rt] = a;
        }
        #pragma unroll
        for (int ct = 0; ct < 2; ++ct)
            #pragma unroll
            for (int rt = 0; rt < 4; ++rt) {
                floatx4 d = bias[ct];
                d = __builtin_amdgcn_mfma_f32_16x16x32_f16(wf[ct], af[rt], d, 0, 0, 0);
                half4 hv;
                hv[0] = (_Float16)d[0]; hv[1] = (_Float16)d[1];
                hv[2] = (_Float16)d[2]; hv[3] = (_Float16)d[3];
                *(half4*)&sOut[(rt * 16 + l16) * LDO + wave * 32 + ct * 16 + quad * 4] = hv;
            }
        __syncthreads();
        #pragma unroll
        for (int p = 0; p < 4; ++p) {
            int idx = p * 256 + t;
            int r = idx >> 4, c = idx & 15;
            int node = base + r;
            if (node < N)
                *(half8*)(nodeEmb + (size_t)node * HID + c * 8) =
                    *(const half8*)&sOut[r * LDO + c * 8];
        }
        __syncthreads();
    }
}

// ---------------------------------------------------------------------------
// Kernel 2: per-edge MLP. TILE_M=32, 512 threads = 8 waves x 16 output cols.
// Geometry proven by r8 (LDS 34.3 KB -> 4 blocks/CU, 91.5% occupancy).
// RACE FIX vs r9/r10: those failed nondeterministically (absmax 0.23/0.22)
// with provably-correct index math and full __syncthreads — implicating
// global_load_lds (its LDS-write completion drain at barriers is compiler-
// modeled; the failure window opened when TILE_M=32 halved the compute
// cover between DMA issue and next-tile consumption; r0-r6 had 2x cover,
// r8's spills accidentally covered it). This version REMOVES global_load_lds
// entirely: REGISTER-STAGED gather (global_load -> va regs -> ds_write).
// Data flows through registers, so waits are enforced by ordinary dataflow,
// and ds_writes drain at __syncthreads via lgkmcnt — correct by the
// standard memory model, no builtins, no inline asm. Loads issue post-B2,
// ds_writes after layer-2 (T14 split); 24-32 waves/CU cover the latency.
// launch_bounds(512,4): natural allocation (~64-76 regs), no spill
// (r8's (512,8) forced 64-unified -> 2GB spill).
// Verify: passed=true (go/no-go), VGPR 64-76, WRITE ~41MB, Occ 60-90%.
// ---------------------------------------------------------------------------
__global__ __launch_bounds__(512, 4) void edge_mlp_kernel(
    const _Float16* __restrict__ nodeEmb,
    const float* __restrict__ pos,
    const int* __restrict__ eidx,          // [2][E]
    const float* __restrict__ W1, const float* __restrict__ b1,   // [257][128]
    const float* __restrict__ W2, const float* __restrict__ b2,   // [128][128]
    const float* __restrict__ W3, const float* __restrict__ b3,   // [128][4]
    float* __restrict__ out, int E, int nTiles)
{
    __shared__ __align__(16) _Float16 sA[2 * TILE_M * HID];   // 16 KB, XOR swizzle
    __shared__ __align__(16) _Float16 sH1[TILE_M * HID];      // 8 KB, XOR swizzle
    __shared__ __align__(16) _Float16 sH2[TILE_M * HID];      // 8 KB, XOR swizzle
    __shared__ float sDist[TILE_M];
    __shared__ __align__(16) _Float16 sW3[512];               // 1 KB  W3 frags

    const int t    = threadIdx.x;
    const int wave = t >> 6;               // 0..7
    const int lane = t & 63;
    const int quad = lane >> 4;
    const int l16  = lane & 15;
    const int colbase = wave * 16;         // each wave owns 16 output columns

    // ---- stage W3 fragment table into LDS (visible after first B1) ----
    if (t < 64) {
        int kc = t >> 4, q = (t >> 2) & 3, c = t & 3;
        #pragma unroll
        for (int j = 0; j < 8; ++j)
            sW3[(kc * 16 + q * 4 + c) * 8 + j] =
                (_Float16)W3[(kc * 32 + q * 8 + j) * 4 + c];
    }

    // ---- weight fragments (frag[j] = W[k0+quad*8+j][col]), 1 col-tile/wave ----
    half8 w1f[8];                          // 32 VGPR
    half8 w2f[4];                          // 16 VGPR
    float w1c[4], b1f[4], b2f[4];
    {
        int col = colbase + l16;
        #pragma unroll
        for (int kc = 0; kc < 8; ++kc)
            #pragma unroll
            for (int j = 0; j < 8; ++j)
                w1f[kc][j] = (_Float16)W1[(kc * 32 + quad * 8 + j) * HID + col];
        #pragma unroll
        for (int kc = 0; kc < 4; ++kc)
            #pragma unroll
            for (int j = 0; j < 8; ++j)
                w2f[kc][j] = (_Float16)W2[(kc * 32 + quad * 8 + j) * HID + col];
        #pragma unroll
        for (int i = 0; i < 4; ++i) {
            int c2 = colbase + quad * 4 + i;
            w1c[i] = W1[256 * HID + c2];
            b1f[i] = b1[c2];
            b2f[i] = b2[c2];
        }
    }
    const float b3v0 = b3[0], b3v1 = b3[1], b3v2 = b3[2], b3v3 = b3[3];

    int nid[2];
    float dpre = 0.f;

    auto load_nid = [&](int tl) {
        int eb = tl * TILE_M;
        #pragma unroll
        for (int i = 0; i < 2; ++i) {
            int cid = i * 512 + t;           // 0..1023 chunks of 16B
            int row = cid >> 4;              // 0..63: 0-31 src, 32-63 dst
            int r   = row & 31;
            int e   = eb + r; if (e >= E) e = E - 1;
            nid[i] = (row >> 5) ? eidx[(size_t)E + e] : eidx[e];
        }
    };
    auto load_dist = [&](int tl) -> float {
        if (t >= TILE_M) return 0.f;
        int e = tl * TILE_M + t; if (e >= E) e = E - 1;
        int s = eidx[e], d = eidx[(size_t)E + e];
        float dx = pos[3 * (size_t)s]     - pos[3 * (size_t)d];
        float dy = pos[3 * (size_t)s + 1] - pos[3 * (size_t)d + 1];
        float dz = pos[3 * (size_t)s + 2] - pos[3 * (size_t)d + 2];
        return sqrtf(dx * dx + dy * dy + dz * dz);
    };
    // register-staged gather: global -> va (dataflow-tracked) ...
    auto gather_issue = [&](half8 va[2]) {
        #pragma unroll
        for (int i = 0; i < 2; ++i) {
            int cid = i * 512 + t;
            int row = cid >> 4;
            int cg  = (cid & 15) ^ (row & 15);      // XOR swizzle
            va[i] = *(const half8*)(nodeEmb + (size_t)nid[i] * HID + cg * 8);
        }
    };
    // ... -> ds_write (drained by lgkmcnt at next __syncthreads)
    auto gather_write = [&](const half8 va[2]) {
        #pragma unroll
        for (int i = 0; i < 2; ++i) {
            int cid = i * 512 + t;
            *(half8*)&sA[cid * 8] = va[i];
        }
    };

    bool havePrev = false;
    int prevEbase = 0;
    int tile = blockIdx.x;
    if (tile < nTiles) {
        load_nid(tile);
        dpre = load_dist(tile);
        half8 va0[2];
        gather_issue(va0);
        gather_write(va0);                   // published by first B1 (lgkm)
    }

    for (; tile < nTiles; tile += gridDim.x) {
        const int ebase = tile * TILE_M;
        if (t < TILE_M) sDist[t] = dpre;
        __syncthreads();                     // B1: sA(T) + sH2(T-1) visible

        // ---- layer 3 of previous tile: waves 0-1 cover the 32 edges ----
        if (havePrev && wave < 2) {
            floatx4 acc3 = (floatx4){0.f, 0.f, 0.f, 0.f};
            #pragma unroll
            for (int kc = 0; kc < 4; ++kc) {
                int slot = ((kc * 4 + quad) ^ l16) * 8;
                half8 h  = *(const half8*)&sH2[(wave * 16 + l16) * HID + slot];
                half8 w3 = *(const half8*)&sW3[(kc * 16 + quad * 4 + (l16 & 3)) * 8];
                acc3 = __builtin_amdgcn_mfma_f32_16x16x32_f16(w3, h, acc3, 0, 0, 0);
            }
            if (quad == 0) {
                int e = prevEbase + wave * 16 + l16;
                if (e < E) {
                    float4 o = {acc3[0] + b3v0, acc3[1] + b3v1,
                                acc3[2] + b3v2, acc3[3] + b3v3};
                    *(float4*)&out[(size_t)e * 4] = o;
                }
            }
        }

        // ---- prefetch next tile metadata (gather issued post-B2) ----
        int nxt = tile + gridDim.x;
        if (nxt < nTiles) {
            load_nid(nxt);
            dpre = load_dist(nxt);
        }

        // ---- layer 1: bias in acc init, XOR-swizzled sA reads ----
        floatx4 acc[2];
        #pragma unroll
        for (int rt = 0; rt < 2; ++rt) {
            acc[rt][0] = b1f[0]; acc[rt][1] = b1f[1];
            acc[rt][2] = b1f[2]; acc[rt][3] = b1f[3];
        }
        #pragma unroll
        for (int kc = 0; kc < 8; ++kc) {
            int hf   = kc >> 2;
            int cg   = (kc & 3) * 4 + quad;
            int slot = (cg ^ l16) * 8;
            const _Float16* base = &sA[(hf * TILE_M + l16) * HID + slot];
            half8 a0 = *(const half8*)(base + 0 * 16 * HID);
            half8 a1 = *(const half8*)(base + 1 * 16 * HID);
            acc[0] = __builtin_amdgcn_mfma_f32_16x16x32_f16(w1f[kc], a0, acc[0], 0, 0, 0);
            acc[1] = __builtin_amdgcn_mfma_f32_16x16x32_f16(w1f[kc], a1, acc[1], 0, 0, 0);
        }
        // epilogue 1 -> sH1 (XOR-swizzled uint2 writes)
        #pragma unroll
        for (int rt = 0; rt < 2; ++rt) {
            int m = rt * 16 + l16;
            float d = sDist[m];
            float v0 = fast_silu(fmaf(d, w1c[0], acc[rt][0]));
            float v1 = fast_silu(fmaf(d, w1c[1], acc[rt][1]));
            float v2 = fast_silu(fmaf(d, w1c[2], acc[rt][2]));
            float v3 = fast_silu(fmaf(d, w1c[3], acc[rt][3]));
            uint2 w;
            w.x = pk2(v0, v1);
            w.y = pk2(v2, v3);
            int cgb  = wave * 2 + (quad >> 1);
            int slot = cgb ^ l16;
            *(uint2*)&sH1[m * HID + slot * 8 + (quad & 1) * 4] = w;
        }
        __syncthreads();                     // B2: h1 visible, sA(T) reads done

        // ---- issue next-tile gather loads (regs only; latency hides under
        //      layer-2; ds_write deferred until after layer-2's MFMAs) ----
        half8 va[2];
        if (nxt < nTiles) gather_issue(va);

        // ---- layer 2 ----
        floatx4 acc2[2];
        #pragma unroll
        for (int rt = 0; rt < 2; ++rt) {
            acc2[rt][0] = b2f[0]; acc2[rt][1] = b2f[1];
            acc2[rt][2] = b2f[2]; acc2[rt][3] = b2f[3];
        }
        #pragma unroll
        for (int kc = 0; kc < 4; ++kc) {
            int slot = ((kc * 4 + quad) ^ l16) * 8;
            half8 a0 = *(const half8*)&sH1[(0 * 16 + l16) * HID + slot];
            half8 a1 = *(const half8*)&sH1[(1 * 16 + l16) * HID + slot];
            acc2[0] = __builtin_amdgcn_mfma_f32_16x16x32_f16(w2f[kc], a0, acc2[0], 0, 0, 0);
            acc2[1] = __builtin_amdgcn_mfma_f32_16x16x32_f16(w2f[kc], a1, acc2[1], 0, 0, 0);
        }

        // ---- ds_write the gathered tile into sA (sA dead since B2) ----
        if (nxt < nTiles) gather_write(va);

        // epilogue 2 -> sH2 (all waves' L3(T-1) reads finished before B2)
        #pragma unroll
        for (int rt = 0; rt < 2; ++rt) {
            int m = rt * 16 + l16;
            float v0 = fast_silu(acc2[rt][0]);
            float v1 = fast_silu(acc2[rt][1]);
            float v2 = fast_silu(acc2[rt][2]);
            float v3 = fast_silu(acc2[rt][3]);
            uint2 w;
            w.x = pk2(v0, v1);
            w.y = pk2(v2, v3);
            int cgb  = wave * 2 + (quad >> 1);
            int slot = cgb ^ l16;
            *(uint2*)&sH2[m * HID + slot * 8 + (quad & 1) * 4] = w;
        }
        havePrev = true;
        prevEbase = ebase;
    }

    // ---- flush: layer 3 of the final tile ----
    if (havePrev) {
        __syncthreads();
        if (wave < 2) {
            floatx4 acc3 = (floatx4){0.f, 0.f, 0.f, 0.f};
            #pragma unroll
            for (int kc = 0; kc < 4; ++kc) {
                int slot = ((kc * 4 + quad) ^ l16) * 8;
                half8 h  = *(const half8*)&sH2[(wave * 16 + l16) * HID + slot];
                half8 w3 = *(const half8*)&sW3[(kc * 16 + quad * 4 + (l16 & 3)) * 8];
                acc3 = __builtin_amdgcn_mfma_f32_16x16x32_f16(w3, h, acc3, 0, 0, 0);
            }
            if (quad == 0) {
                int e = prevEbase + wave * 16 + l16;
                if (e < E) {
                    float4 o = {acc3[0] + b3v0, acc3[1] + b3v1,
                                acc3[2] + b3v2, acc3[3] + b3v3};
                    *(float4*)&out[(size_t)e * 4] = o;
                }
            }
        }
    }
}

extern "C" void kernel_launch(void* const* d_in, const int* in_sizes, int n_in,
                              void* d_out, int out_size, void* d_ws, size_t ws_size,
                              hipStream_t stream) {
    const float* x   = (const float*)d_in[0];
    const float* pos = (const float*)d_in[1];
    const int*  eidx = (const int*)d_in[2];
    const float* Wa = (const float*)d_in[3];
    const float* ba = (const float*)d_in[4];
    const float* Wp = (const float*)d_in[5];
    const float* bp = (const float*)d_in[6];
    const float* W1 = (const float*)d_in[7];
    const float* b1 = (const float*)d_in[8];
    const float* W2 = (const float*)d_in[9];
    const float* b2 = (const float*)d_in[10];
    const float* W3 = (const float*)d_in[11];
    const float* b3 = (const float*)d_in[12];
    float* out = (float*)d_out;

    int N = in_sizes[0] / 16;   // ATOM_DIM
    int E = in_sizes[2] / 2;

    _Float16* nodeEmb = (_Float16*)d_ws;   // N*128 fp16 = 25.6 MB

    int nodeTiles = (N + 63) / 64;
    node_emb_kernel<<<nodeTiles, 256, 0, stream>>>(x, pos, Wa, ba, Wp, bp, nodeEmb, N);

    int nTiles = (E + TILE_M - 1) / TILE_M;
    // 4 blocks/CU x 256 CUs, 512 threads each
    edge_mlp_kernel<<<1024, 512, 0, stream>>>(nodeEmb, pos, eidx,
                                              W1, b1, W2, b2, W3, b3,
                                              out, E, nTiles);
}